// Round 5
// baseline (27.268 us; speedup 1.0000x reference)
//
#include <hip/hip_runtime.h>

// Not-a-knot cubic spline upsample (512 x 8192 f32 -> 512 x 32768 f32).
//
// [1,4,1] Toeplitz inverse = C * r^|i-j|, r = sqrt(3)-2, C = 1/(2*sqrt(3)).
// Interior tiles: fold the 6*second-difference into the Green's function ->
// direct 25-tap conv on y:  M[j] = W0*y[j] + sum_d Wd*(y[j-d]+y[j+d]),
//   W0 = 6-6*sqrt(3), Wd = sqrt(3)*(1-r)^2 * r^(d-1), d = 1..12.
// Conv threads (t=0..128) read ys[4t..4t+31] via 8 aligned ds_read_b128 and
// produce 4 knots each, written INTERLEAVED as ym[idx] = (y[j], M[j]) so the
// eval phase needs only 3 ds_read_b64 per 4 outputs.
// Boundary tiles (first/last): reflected-RHS route (R1-proven), K=10.
// Stores are plain (NOT nontemporal): out (64MB) + in (17MB) fit the 256MB
// L3, which retains/re-dirties the same lines across timed replays.

typedef float  f32x4 __attribute__((ext_vector_type(4)));
typedef float  f32x2 __attribute__((ext_vector_type(2)));

constexpr int W    = 8192;
constexpr int WU   = 32768;
constexpr int TILE = 512;
constexpr int HL   = 16;                 // left halo; keeps main tile 16B-aligned
constexpr int YSN  = 544;                // ys[idx] = x[s0-16+idx], idx in [0,543]
constexpr int MSN  = 516;                // ym[idx] = (y,M) at knot j = s0-1+idx
constexpr int KB   = 10;                 // boundary bt-path half width
constexpr int BTN  = 538;                // bt[idx] = b(s0-13+idx)

__global__ __launch_bounds__(256)
void spline_kernel(const float* __restrict__ x, float* __restrict__ out)
{
    const int row = blockIdx.y;
    const int s0  = blockIdx.x * TILE;
    const int tid = threadIdx.x;
    const int n   = W - 4;               // unknowns M[2..W-3]

    __shared__ __align__(16) float ys[YSN];
    __shared__ __align__(16) f32x2 ym[MSN];
    __shared__ float bt[BTN];

    const float* __restrict__ xr = x + (size_t)row * (size_t)W;
    const int YS0 = s0 - HL;

    // ---- stage: aligned float4 main tile + scalar halos (16 each side) ----
    if (tid < 128) {
        f32x4 v = *(const f32x4*)(xr + s0 + 4 * tid);
        *(f32x4*)&ys[HL + 4 * tid] = v;
    } else if (tid < 128 + 16) {
        int idx = tid - 128;                       // 0..15 -> ys[0..15]
        int g = YS0 + idx; if (g < 0) g = 0;       // clamped entries never used
        ys[idx] = xr[g];
    } else if (tid < 128 + 32) {
        int idx = tid - (128 + 16);                // 0..15 -> ys[528..543]
        int g = s0 + TILE + idx; if (g > W - 1) g = W - 1;
        ys[HL + TILE + idx] = xr[g];
    }
    __syncthreads();

    const bool boundary = (blockIdx.x == 0) || (blockIdx.x == gridDim.x - 1);

    if (!boundary) {
        // ---- interior: 4 knots/thread, 8x ds_read_b128 window ----
        if (tid < 129) {
            const f32x4* ys4 = (const f32x4*)ys;
            float w[32];
            #pragma unroll
            for (int k = 0; k < 8; ++k) {          // w[m] = ys[4*tid+m]
                f32x4 v = ys4[tid + k];
                w[4*k+0] = v.x; w[4*k+1] = v.y; w[4*k+2] = v.z; w[4*k+3] = v.w;
            }
            float acc[4];
            #pragma unroll
            for (int c = 0; c < 4; ++c)
                acc[c] = -4.39230484541326386f * w[15 + c];
            float wd = 2.78460969082652752f;       // sqrt(3)*(1-r)^2
            #pragma unroll
            for (int d = 1; d <= 12; ++d) {
                #pragma unroll
                for (int c = 0; c < 4; ++c)
                    acc[c] += wd * (w[15 + c - d] + w[15 + c + d]);
                wd *= -0.26794919243112270647f;    // folds to literals
            }
            f32x4 o0 = {w[15], acc[0], w[16], acc[1]};
            f32x4 o1 = {w[17], acc[2], w[18], acc[3]};
            *(f32x4*)&ym[4 * tid]     = o0;
            *(f32x4*)&ym[4 * tid + 2] = o1;
        }
    } else {
        // ---- boundary: reflected-RHS Green's conv (R1-proven) ----
        auto Dp = [&](int p) -> float {
            int a = p - YS0;
            return 6.0f * (ys[a + 1] - 2.0f * ys[a] + ys[a - 1]);
        };
        auto M1v = [&]() -> float {
            int a = -YS0; return ys[a] - 2.0f * ys[a + 1] + ys[a + 2];
        };
        auto Mn2v = [&]() -> float {
            int a = (W - 1) - YS0; return ys[a] - 2.0f * ys[a - 1] + ys[a - 2];
        };
        auto bval = [&](int m) -> float {
            if (m == -1 || m == n) return 0.0f;
            float sgn = 1.0f;
            if (m < -1)     { m = -2 - m;   sgn = -1.0f; }
            else if (m > n) { m = 2 * n - m; sgn = -1.0f; }
            float v = Dp(m + 2);
            if (m == 0)     v -= M1v();
            if (m == n - 1) v -= Mn2v();
            return sgn * v;
        };
        const int BT0 = s0 - 3 - KB;
        for (int idx = tid; idx < BTN; idx += 256)
            bt[idx] = bval(BT0 + idx);
        __syncthreads();
        auto convb = [&](int j) -> float {
            int base = j - 2 - BT0;
            float acc = 0.288675134594812882f * bt[base];
            float wr  = 0.288675134594812882f;
            #pragma unroll
            for (int d = 1; d <= KB; ++d) {
                wr  *= -0.26794919243112270647f;
                acc += wr * (bt[base - d] + bt[base + d]);
            }
            return acc;
        };
        for (int idx = tid; idx < MSN; idx += 256) {
            int j = s0 - 1 + idx;
            j = j < 0 ? 0 : (j > W - 1 ? W - 1 : j);
            float m;
            if (j == 0)          m = 2.0f * M1v() - convb(2);
            else if (j == 1)     m = M1v();
            else if (j == W - 2) m = Mn2v();
            else if (j == W - 1) m = 2.0f * Mn2v() - convb(W - 3);
            else                 m = convb(j);
            ym[idx] = (f32x2){ys[idx + 15], m};
        }
    }
    __syncthreads();

    // ---- eval: exact integer i,t; 4 outputs/thread-iter; float4 store ----
    float* __restrict__ orow = out + (size_t)row * (size_t)WU;
    const int qbase = s0 * (WU / W);
    #pragma unroll
    for (int it = 0; it < 2; ++it) {
        int q0  = qbase + (tid + it * 256) * 4;
        int num = q0 * (W - 1);                  // < 2^31
        int i0  = num / (WU - 1);                // magic-div (constexpr divisor)
        int rr  = num - i0 * (WU - 1);
        int kM  = i0 - s0 + 1;
        f32x2 p0 = ym[kM], p1 = ym[kM + 1], p2 = ym[kM + 2];
        float res[4];
        int di = 0;                              // at most one knot crossing per 4 q
        #pragma unroll
        for (int u = 0; u < 4; ++u) {
            float t  = (float)rr * (1.0f / (float)(WU - 1));
            float y0 = di ? p1.x : p0.x;
            float y1 = di ? p2.x : p1.x;
            float m0 = di ? p1.y : p0.y;
            float m1 = di ? p2.y : p1.y;
            float bb = (y1 - y0) - (2.0f * m0 + m1) * (1.0f / 6.0f);
            res[u] = y0 + t * (bb + t * (0.5f * m0 + t * (m1 - m0) * (1.0f / 6.0f)));
            rr += (W - 1);
            if (rr >= WU - 1) { rr -= (WU - 1); di = 1; }
        }
        f32x4 o = (f32x4){res[0], res[1], res[2], res[3]};
        *(f32x4*)(orow + q0) = o;
    }
}

extern "C" void kernel_launch(void* const* d_in, const int* in_sizes, int n_in,
                              void* d_out, int out_size, void* d_ws, size_t ws_size,
                              hipStream_t stream) {
    const float* x = (const float*)d_in[0];
    float* out = (float*)d_out;
    const int B = in_sizes[0] / W;               // 512
    dim3 grid(W / TILE, B), block(256);
    hipLaunchKernelGGL(spline_kernel, grid, block, 0, stream, x, out);
}